// Round 1
// baseline (2316.490 us; speedup 1.0000x reference)
//
#include <hip/hip_runtime.h>
#include <hip/hip_bf16.h>

// Problem constants
#define BB 16
#define NN 8192
#define SS 1024
#define GG 32
// sortable(1.0f) = 0x3F800000 ^ 0x80000000
#define SORT_R2 0xBF800000u

typedef float v2f __attribute__((ext_vector_type(2)));

__device__ __forceinline__ unsigned sortable(float f) {
    unsigned u = __float_as_uint(f);
    return u ^ ((unsigned)(((int)u) >> 31) | 0x80000000u);
}

// f32 max-combine with a DPP-permuted copy (2 slots: v_mov_dpp + v_max_f32).
// row_shr:n = 0x110|n, row_bcast15 = 0x142, row_bcast31 = 0x143.
template <int CTRL, int RM>
__device__ __forceinline__ float dpp_maxf(float v) {
    int i = __float_as_int(v);
    int p = __builtin_amdgcn_update_dpp(i, i, CTRL, RM, 0xF, false);
    return fmaxf(v, __int_as_float(p));
}

// u32 min-combine with a DPP-permuted copy (2 slots).
template <int CTRL, int RM>
__device__ __forceinline__ unsigned dpp_minu(unsigned v) {
    int p = __builtin_amdgcn_update_dpp((int)v, (int)v, CTRL, RM, 0xF, false);
    return min(v, (unsigned)p);
}

__device__ __forceinline__ float fmax3(float a, float b, float c) {
    return fmaxf(fmaxf(a, b), c);   // fuses to v_max3_f32
}

// ---------------------------------------------------------------------------
// Kernel 1: pack pts4[b][n] = {x, y, z, (x*x+y*y)+z*z}  (rn ops, no contraction)
// ---------------------------------------------------------------------------
__global__ __launch_bounds__(256) void k_pts(const float* __restrict__ coor,
                                             float4* __restrict__ pts4) {
    int i = blockIdx.x * 256 + threadIdx.x;   // 0 .. B*N-1
    int b = i >> 13, n = i & (NN - 1);
    const float* cb = coor + (long)b * 3 * NN;
    float x = cb[n], y = cb[NN + n], z = cb[2 * NN + n];
    float pn = __fadd_rn(__fadd_rn(__fmul_rn(x, x), __fmul_rn(y, y)), __fmul_rn(z, z));
    pts4[i] = make_float4(x, y, z, pn);
}

// ---------------------------------------------------------------------------
// Kernel 2: transpose fea (B,64,N) -> feaT (B,N,64)
// ---------------------------------------------------------------------------
__global__ __launch_bounds__(256) void k_tr(const float* __restrict__ fea,
                                            float* __restrict__ feaT) {
    __shared__ float tile[64][65];
    int b = blockIdx.y, n0 = blockIdx.x * 64;
    int t = threadIdx.x;
    int nl = t & 63, cb = t >> 6;
#pragma unroll
    for (int i = 0; i < 16; i++) {
        int c = cb * 16 + i;
        tile[nl][c] = fea[((long)b * 64 + c) * NN + n0 + nl];
    }
    __syncthreads();
    int cl = t & 63, nb = t >> 6;
#pragma unroll
    for (int i = 0; i < 16; i++) {
        int n = nb * 16 + i;
        feaT[((long)b * NN + n0 + n) * 64 + cl] = tile[n][cl];
    }
}

// ---------------------------------------------------------------------------
// Kernel 3: farthest point sampling. One block per batch.
// R13: wave-count REDUCTION 8 -> 2 (512 -> 128 threads). The measured
// ~2200 cyc/step floor at 8 waves was sync-dominated (two barrier
// round-trips + arrival skew + 2-waves/SIMD issue sharing); VALU issue
// was only ~470 of those cycles. With 2 waves (one per SIMD, 64 pts/lane
// = 32 v2f pairs, 256 VGPRs of point data, 1 wave/SIMD so no sharing and
// no spill at __launch_bounds__(128,1)) the barrier population drops 4x
// while the reduction structure stays verbatim: value-only f32 DPP wave
// max -> 2-entry LDS combine -> rare equality scan + LDS atomicMin on the
// smallest point index. Same rn ops, contract(off): bit-exact vs R12.
// ---------------------------------------------------------------------------
__global__ __launch_bounds__(128, 1) void k_fps(const float4* __restrict__ pts4,
                                                float4* __restrict__ qpts,
                                                float* __restrict__ out) {
#pragma clang fp contract(off)
    __shared__ float xs[NN], ys[NN], zs[NN];
    __shared__ int scur[SS];
    __shared__ __align__(16) float redv[2][2];
    __shared__ int sidx[2];
    int b = blockIdx.x;
    int t = threadIdx.x;
    const float4* P = pts4 + (long)b * NN;

    // pair j, half h -> point p = t + (2j+h)*128
    v2f px[32], py[32], pz[32], dist[32];
#pragma unroll
    for (int j = 0; j < 32; j++) {
        int p0 = t + (2 * j) * 128;
        int p1 = t + (2 * j + 1) * 128;
        float4 a = P[p0];
        float4 c = P[p1];
        px[j] = v2f{a.x, c.x};
        py[j] = v2f{a.y, c.y};
        pz[j] = v2f{a.z, c.z};
        dist[j] = v2f{1e10f, 1e10f};
        xs[p0] = a.x; ys[p0] = a.y; zs[p0] = a.z;
        xs[p1] = c.x; ys[p1] = c.y; zs[p1] = c.z;
    }
    if (t == 0) { sidx[0] = 0x7FFFFFFF; sidx[1] = 0x7FFFFFFF; }
    __syncthreads();

    int cur = 0;
    for (int s = 0; s < SS; s++) {
        int par = s & 1;
        float cx = xs[cur], cy = ys[cur], cz = zs[cur];
        if (t == 0) scur[s] = cur;
        v2f cx2 = v2f{cx, cx}, cy2 = v2f{cy, cy}, cz2 = v2f{cz, cz};
#pragma unroll
        for (int j = 0; j < 32; j++) {
            v2f dx = px[j] - cx2;
            v2f dy = py[j] - cy2;
            v2f dz = pz[j] - cz2;
            v2f xx = dx * dx;
            v2f yy = dy * dy;
            v2f zz = dz * dz;
            v2f sm = xx + yy;
            v2f d = sm + zz;
            dist[j] = __builtin_elementwise_min(dist[j], d);
        }
        // value-only per-thread max: packed tree (31 pk-max) + final scalar
        v2f a[16], c[8], e[4], f[2];
#pragma unroll
        for (int j = 0; j < 16; j++) a[j] = __builtin_elementwise_max(dist[2 * j], dist[2 * j + 1]);
#pragma unroll
        for (int j = 0; j < 8; j++) c[j] = __builtin_elementwise_max(a[2 * j], a[2 * j + 1]);
#pragma unroll
        for (int j = 0; j < 4; j++) e[j] = __builtin_elementwise_max(c[2 * j], c[2 * j + 1]);
#pragma unroll
        for (int j = 0; j < 2; j++) f[j] = __builtin_elementwise_max(e[2 * j], e[2 * j + 1]);
        v2f m07 = __builtin_elementwise_max(f[0], f[1]);
        float bv = fmaxf(m07.x, m07.y);
        // 64-lane DPP f32 max; full-wave max lands in lane 63
        float wv = bv;
        wv = dpp_maxf<0x111, 0xF>(wv);   // row_shr:1
        wv = dpp_maxf<0x112, 0xF>(wv);   // row_shr:2
        wv = dpp_maxf<0x114, 0xF>(wv);   // row_shr:4
        wv = dpp_maxf<0x118, 0xF>(wv);   // row_shr:8
        wv = dpp_maxf<0x142, 0xA>(wv);   // row_bcast:15 (rows 1,3)
        wv = dpp_maxf<0x143, 0xC>(wv);   // row_bcast:31 (rows 2,3)
        if ((t & 63) == 63) redv[par][t >> 6] = wv;
        __syncthreads();                 // barrier 1
        float2 r = *(const float2*)redv[par];
        float gmax = fmaxf(r.x, r.y);
        // reset the OTHER sidx slot (used at s+1); barrier 2 separates it
        // from s+1's atomics.
        if (t == 0) sidx[1 - par] = 0x7FFFFFFF;
        if (bv == gmax) {
            // block-rare path (usually 1 thread): lowest matching ord
            int jj = 64;
#pragma unroll
            for (int j = 31; j >= 0; j--) {
                jj = (dist[j].y == gmax) ? (2 * j + 1) : jj;
                jj = (dist[j].x == gmax) ? (2 * j) : jj;
            }
            atomicMin(&sidx[par], t + jj * 128);
        }
        __syncthreads();                 // barrier 2
        cur = sidx[par];
    }
    __syncthreads();

    // epilogue: write new_coor (B,3,S) and query points from recorded indices
#pragma unroll
    for (int s = t; s < SS; s += 128) {
        int c = scur[s];
        float cx = xs[c], cy = ys[c], cz = zs[c];
        out[(long)b * 3 * SS + s]          = cx;
        out[(long)b * 3 * SS + SS + s]     = cy;
        out[(long)b * 3 * SS + 2 * SS + s] = cz;
        float qn = __fadd_rn(__fadd_rn(__fmul_rn(cx, cx), __fmul_rn(cy, cy)),
                             __fmul_rn(cz, cz));
        qpts[(long)b * SS + s] = make_float4(cx, cy, cz, qn);
    }
}

// ---------------------------------------------------------------------------
// Kernel 4 (FUSED knn+mlp): R12 structure (passed, absmax 0.0), with the MLP
// phase packed: output-channel pairs (a0,a1) accumulate via v_pk_fma_f32
// (__builtin_elementwise_fma on v2f, weights interleaved wab[c]={wa,wb}).
// Each half is the same IEEE fma in the same order as the scalar fmaf
// version -> bit-identical results, half the VALU issue (4352 -> 2176
// fma-slots per thread).
// ---------------------------------------------------------------------------
#define SKEW(p) ((p) + ((p) >> 5))
__global__ __launch_bounds__(64, 1) void k_knn_mlp(const float4* __restrict__ pts4,
                                                   const float* __restrict__ feaT,
                                                   const float4* __restrict__ qpts,
                                                   const float* __restrict__ W,
                                                   float* __restrict__ out) {
    __shared__ __align__(16) unsigned dk[NN + NN / 32];   // 33792 B
    __shared__ int sidxs[GG];
    float* grouped = (float*)dk;   // reused after pops: 32*68 floats (8704 B)

    int Q = blockIdx.x;                      // b*1024 + s
    int b = Q >> 10, s = Q & 1023;
    int l = threadIdx.x;
    float4 q = qpts[Q];
    const float4* P = pts4 + (long)b * NN;

    // ---- Phase 1: distance scan ----
    unsigned bmin = 0xFFFFFFFFu;
    int bpos = 0;
#pragma unroll 16
    for (int j = 0; j < 128; j++) {
        int p = j * 64 + l;
        float4 v = P[p];
        float dot = __fadd_rn(__fadd_rn(__fmul_rn(q.x, v.x), __fmul_rn(q.y, v.y)),
                              __fmul_rn(q.z, v.z));
        float d = __fadd_rn(__fsub_rn(q.w, __fmul_rn(2.0f, dot)), v.w);
        unsigned u = sortable(d);
        dk[SKEW(p)] = u;
        if (u < bmin) { bmin = u; bpos = p; }   // ascending p -> earliest index on tie
    }
    __syncthreads();

    // ---- Phase 2: W rows into registers, interleaved (latency overlaps pops) ----
    v2f wab[68];
    {
        const float* Wr = W + l * 67;
#pragma unroll
        for (int c = 0; c < 67; c++) {
            wab[c] = v2f{Wr[c], Wr[64 * 67 + c]};
        }
        wab[67] = v2f{0.f, 0.f};
    }

    // ---- Phase 3: 32 pops ----
    unsigned resv = 0;
    int resp = 0, pos0 = 0;
    for (int k = 0; k < GG; k++) {
        unsigned mv = bmin;
        mv = dpp_minu<0x111, 0xF>(mv);
        mv = dpp_minu<0x112, 0xF>(mv);
        mv = dpp_minu<0x114, 0xF>(mv);
        mv = dpp_minu<0x118, 0xF>(mv);
        mv = dpp_minu<0x142, 0xA>(mv);
        mv = dpp_minu<0x143, 0xC>(mv);
        unsigned wmin = (unsigned)__builtin_amdgcn_readlane((int)mv, 63);
        unsigned long long mask = __ballot(bmin == wmin);
        int wpos;
        if (__builtin_popcountll(mask) == 1) {
            int owner = __builtin_ctzll(mask);
            wpos = __builtin_amdgcn_readlane(bpos, owner);
        } else {
            unsigned long long kk =
                ((unsigned long long)bmin << 32) | (unsigned)bpos;
#pragma unroll
            for (int m = 1; m < 64; m <<= 1) {
                unsigned long long o = __shfl_xor(kk, m, 64);
                kk = (o < kk) ? o : kk;
            }
            wpos = (int)(kk & 0xFFFFFFFFull);
        }
        if (k == 0) pos0 = wpos;
        if (l == k) { resv = wmin; resp = wpos; }
        int own = wpos & 63;
        if (l == own) dk[SKEW(wpos)] = 0xFFFFFFFFu;   // invalidate popped slot
        __syncthreads();
        // cooperative rescan of owner's column (its 128 points)
        int p1 = l * 64 + own;
        int p2 = (l + 64) * 64 + own;
        unsigned v1 = dk[SKEW(p1)], v2 = dk[SKEW(p2)];
        bool c = v2 < v1;                 // p1 < p2, so tie keeps earliest
        unsigned cv = c ? v2 : v1;
        int cp = c ? p2 : p1;
        unsigned cm = cv;
        cm = dpp_minu<0x111, 0xF>(cm);
        cm = dpp_minu<0x112, 0xF>(cm);
        cm = dpp_minu<0x114, 0xF>(cm);
        cm = dpp_minu<0x118, 0xF>(cm);
        cm = dpp_minu<0x142, 0xA>(cm);
        cm = dpp_minu<0x143, 0xC>(cm);
        unsigned colmin = (unsigned)__builtin_amdgcn_readlane((int)cm, 63);
        unsigned long long m2 = __ballot(cv == colmin);
        int colpos;
        if (__builtin_popcountll(m2) == 1) {
            colpos = __builtin_amdgcn_readlane(cp, __builtin_ctzll(m2));
        } else {
            unsigned long long kk =
                ((unsigned long long)cv << 32) | (unsigned)cp;
#pragma unroll
            for (int m = 1; m < 64; m <<= 1) {
                unsigned long long o = __shfl_xor(kk, m, 64);
                kk = (o < kk) ? o : kk;
            }
            colpos = (int)(kk & 0xFFFFFFFFull);
        }
        if (l == own) { bmin = colmin; bpos = colpos; }
        __syncthreads();
    }

    // ---- Phase 4: final indices + gather into reused LDS ----
    if (l < GG) sidxs[l] = (resv > SORT_R2) ? pos0 : resp;   // radius filter
    __syncthreads();   // sidxs visible; dk dead from here on

    if (l < 32) {
        int idx = sidxs[l];
        float4 p = pts4[(long)b * NN + idx];
        float4 rc = make_float4(__fsub_rn(p.x, q.x), __fsub_rn(p.y, q.y),
                                __fsub_rn(p.z, q.z), 0.f);
        *(float4*)&grouped[l * 68 + 64] = rc;
    }
    {
        int g = l >> 1, half = l & 1;
        int idx = sidxs[g];
        const float4* f4 = (const float4*)(feaT + ((long)b * NN + idx) * 64);
#pragma unroll
        for (int k4 = 0; k4 < 8; k4++) {
            *(float4*)&grouped[g * 68 + half * 32 + k4 * 4] = f4[half * 8 + k4];
        }
    }
    __syncthreads();

    // ---- Phase 5: 1x1 conv + relu + max over group (packed pk_fma) ----
    v2f mm = v2f{-1e30f, -1e30f};
#pragma unroll 2
    for (int g = 0; g < GG; g++) {
        v2f a = v2f{0.f, 0.f};
#pragma unroll
        for (int c4 = 0; c4 < 17; c4++) {
            float4 gv = *(float4*)&grouped[g * 68 + c4 * 4];
            a = __builtin_elementwise_fma(v2f{gv.x, gv.x}, wab[4 * c4 + 0], a);
            a = __builtin_elementwise_fma(v2f{gv.y, gv.y}, wab[4 * c4 + 1], a);
            a = __builtin_elementwise_fma(v2f{gv.z, gv.z}, wab[4 * c4 + 2], a);
            a = __builtin_elementwise_fma(v2f{gv.w, gv.w}, wab[4 * c4 + 3], a);
        }
        mm = __builtin_elementwise_max(mm, a);
    }
    // outputs: (B,3,S) then (B,128,S); relu(max) == max(relu)
    out[49152 + ((long)b * 128 + l) * SS + s]      = fmaxf(mm.x, 0.f);
    out[49152 + ((long)b * 128 + l + 64) * SS + s] = fmaxf(mm.y, 0.f);
}

// ---------------------------------------------------------------------------
extern "C" void kernel_launch(void* const* d_in, const int* in_sizes, int n_in,
                              void* d_out, int out_size, void* d_ws, size_t ws_size,
                              hipStream_t stream) {
    const float* coor = (const float*)d_in[0];   // (16,3,8192)
    const float* fea  = (const float*)d_in[1];   // (16,64,8192)
    const float* Wm   = (const float*)d_in[2];   // (128,67)
    float* out = (float*)d_out;

    char* ws = (char*)d_ws;
    float4* pts4 = (float4*)ws;                               //  2 MB
    float*  feaT = (float*)(ws + 2097152);                    // 32 MB
    float4* qpts = (float4*)(ws + 2097152 + 33554432);        // 256 KB

    k_pts<<<(BB * NN) / 256, 256, 0, stream>>>(coor, pts4);
    k_tr<<<dim3(NN / 64, BB), 256, 0, stream>>>(fea, feaT);
    k_fps<<<BB, 128, 0, stream>>>(pts4, qpts, out);
    k_knn_mlp<<<BB * SS, 64, 0, stream>>>(pts4, feaT, qpts, Wm, out);
}

// Round 4
// 1468.334 us; speedup vs baseline: 1.5776x; 1.5776x over previous
//
#include <hip/hip_runtime.h>
#include <hip/hip_bf16.h>

// Problem constants
#define BB 16
#define NN 8192
#define SS 1024
#define GG 32
// sortable(1.0f) = 0x3F800000 ^ 0x80000000
#define SORT_R2 0xBF800000u

typedef float v2f __attribute__((ext_vector_type(2)));

__device__ __forceinline__ unsigned sortable(float f) {
    unsigned u = __float_as_uint(f);
    return u ^ ((unsigned)(((int)u) >> 31) | 0x80000000u);
}

// f32 max-combine with a DPP-permuted copy (2 slots: v_mov_dpp + v_max_f32).
// row_shr:n = 0x110|n, row_bcast15 = 0x142, row_bcast31 = 0x143.
template <int CTRL, int RM>
__device__ __forceinline__ float dpp_maxf(float v) {
    int i = __float_as_int(v);
    int p = __builtin_amdgcn_update_dpp(i, i, CTRL, RM, 0xF, false);
    return fmaxf(v, __int_as_float(p));
}

// u32 min-combine with a DPP-permuted copy (2 slots).
template <int CTRL, int RM>
__device__ __forceinline__ unsigned dpp_minu(unsigned v) {
    int p = __builtin_amdgcn_update_dpp((int)v, (int)v, CTRL, RM, 0xF, false);
    return min(v, (unsigned)p);
}

__device__ __forceinline__ float fmax3(float a, float b, float c) {
    return fmaxf(fmaxf(a, b), c);   // fuses to v_max3_f32
}

// ---------------------------------------------------------------------------
// Kernel 1: pack pts4[b][n] = {x, y, z, (x*x+y*y)+z*z}  (rn ops, no contraction)
// ---------------------------------------------------------------------------
__global__ __launch_bounds__(256) void k_pts(const float* __restrict__ coor,
                                             float4* __restrict__ pts4) {
    int i = blockIdx.x * 256 + threadIdx.x;   // 0 .. B*N-1
    int b = i >> 13, n = i & (NN - 1);
    const float* cb = coor + (long)b * 3 * NN;
    float x = cb[n], y = cb[NN + n], z = cb[2 * NN + n];
    float pn = __fadd_rn(__fadd_rn(__fmul_rn(x, x), __fmul_rn(y, y)), __fmul_rn(z, z));
    pts4[i] = make_float4(x, y, z, pn);
}

// ---------------------------------------------------------------------------
// Kernel 2: transpose fea (B,64,N) -> feaT (B,N,64)
// ---------------------------------------------------------------------------
__global__ __launch_bounds__(256) void k_tr(const float* __restrict__ fea,
                                            float* __restrict__ feaT) {
    __shared__ float tile[64][65];
    int b = blockIdx.y, n0 = blockIdx.x * 64;
    int t = threadIdx.x;
    int nl = t & 63, cb = t >> 6;
#pragma unroll
    for (int i = 0; i < 16; i++) {
        int c = cb * 16 + i;
        tile[nl][c] = fea[((long)b * 64 + c) * NN + n0 + nl];
    }
    __syncthreads();
    int cl = t & 63, nb = t >> 6;
#pragma unroll
    for (int i = 0; i < 16; i++) {
        int n = nb * 16 + i;
        feaT[((long)b * NN + n0 + n) * 64 + cl] = tile[n][cl];
    }
}

// ---------------------------------------------------------------------------
// Kernel 3: farthest point sampling. One block (512 thr) per batch.
// R14: VERBATIM revert to R12 (the measured optimum, ~935 us). R13's
// 128-thread attempt hit the 256-VGPR architected ceiling (VGPR_Count=136
// -> point data spilled to scratch, 1792 us). Six structural attacks
// (issue-count, barrier-count, 2x wave-count, Morton+skip, 2-wave) have
// now all regressed: 512 thr / 2 waves-per-SIMD is the floor config —
// co-wave latency hiding beats lower barrier population.
// ---------------------------------------------------------------------------
__global__ __launch_bounds__(512) void k_fps(const float4* __restrict__ pts4,
                                             float4* __restrict__ qpts,
                                             float* __restrict__ out) {
#pragma clang fp contract(off)
    __shared__ float xs[NN], ys[NN], zs[NN];
    __shared__ int scur[SS];
    __shared__ __align__(16) float redv[2][8];
    __shared__ int sidx[2];
    int b = blockIdx.x;
    int t = threadIdx.x;
    const float4* P = pts4 + (long)b * NN;

    // pair j, half h -> point p = t + (2j+h)*512
    v2f px[8], py[8], pz[8], dist[8];
#pragma unroll
    for (int j = 0; j < 8; j++) {
        int p0 = t + (2 * j) * 512;
        int p1 = t + (2 * j + 1) * 512;
        float4 a = P[p0];
        float4 c = P[p1];
        px[j] = v2f{a.x, c.x};
        py[j] = v2f{a.y, c.y};
        pz[j] = v2f{a.z, c.z};
        dist[j] = v2f{1e10f, 1e10f};
        xs[p0] = a.x; ys[p0] = a.y; zs[p0] = a.z;
        xs[p1] = c.x; ys[p1] = c.y; zs[p1] = c.z;
    }
    if (t == 0) { sidx[0] = 0x7FFFFFFF; sidx[1] = 0x7FFFFFFF; }
    __syncthreads();

    int cur = 0;
    for (int s = 0; s < SS; s++) {
        int par = s & 1;
        float cx = xs[cur], cy = ys[cur], cz = zs[cur];
        if (t == 0) scur[s] = cur;
        v2f cx2 = v2f{cx, cx}, cy2 = v2f{cy, cy}, cz2 = v2f{cz, cz};
#pragma unroll
        for (int j = 0; j < 8; j++) {
            v2f dx = px[j] - cx2;
            v2f dy = py[j] - cy2;
            v2f dz = pz[j] - cz2;
            v2f xx = dx * dx;
            v2f yy = dy * dy;
            v2f zz = dz * dz;
            v2f sm = xx + yy;
            v2f d = sm + zz;
            dist[j] = __builtin_elementwise_min(dist[j], d);
        }
        // value-only per-thread max: packed tree (7 pk-max) + final scalar
        v2f m01 = __builtin_elementwise_max(dist[0], dist[1]);
        v2f m23 = __builtin_elementwise_max(dist[2], dist[3]);
        v2f m45 = __builtin_elementwise_max(dist[4], dist[5]);
        v2f m67 = __builtin_elementwise_max(dist[6], dist[7]);
        v2f m03 = __builtin_elementwise_max(m01, m23);
        v2f m47 = __builtin_elementwise_max(m45, m67);
        v2f m07 = __builtin_elementwise_max(m03, m47);
        float bv = fmaxf(m07.x, m07.y);
        // 64-lane DPP f32 max; full-wave max lands in lane 63
        float wv = bv;
        wv = dpp_maxf<0x111, 0xF>(wv);   // row_shr:1
        wv = dpp_maxf<0x112, 0xF>(wv);   // row_shr:2
        wv = dpp_maxf<0x114, 0xF>(wv);   // row_shr:4
        wv = dpp_maxf<0x118, 0xF>(wv);   // row_shr:8
        wv = dpp_maxf<0x142, 0xA>(wv);   // row_bcast:15 (rows 1,3)
        wv = dpp_maxf<0x143, 0xC>(wv);   // row_bcast:31 (rows 2,3)
        if ((t & 63) == 63) redv[par][t >> 6] = wv;
        __syncthreads();                 // barrier 1
        float4 r0 = *(const float4*)redv[par];
        float4 r1 = *(const float4*)(redv[par] + 4);
        float gmax = fmaxf(fmax3(r0.x, r0.y, r0.z),
                           fmax3(r0.w, fmax3(r1.x, r1.y, r1.z), r1.w));
        // reset the OTHER sidx slot (used at s+1); barrier 2 separates it
        // from s+1's atomics.
        if (t == 0) sidx[1 - par] = 0x7FFFFFFF;
        if (bv == gmax) {
            // block-rare path (usually 1 thread): lowest matching ord
            int jj = 16;
#pragma unroll
            for (int j = 7; j >= 0; j--) {
                jj = (dist[j].y == gmax) ? (2 * j + 1) : jj;
                jj = (dist[j].x == gmax) ? (2 * j) : jj;
            }
            atomicMin(&sidx[par], t + jj * 512);
        }
        __syncthreads();                 // barrier 2
        cur = sidx[par];
    }
    __syncthreads();

    // epilogue: write new_coor (B,3,S) and query points from recorded indices
#pragma unroll
    for (int s = t; s < SS; s += 512) {
        int c = scur[s];
        float cx = xs[c], cy = ys[c], cz = zs[c];
        out[(long)b * 3 * SS + s]          = cx;
        out[(long)b * 3 * SS + SS + s]     = cy;
        out[(long)b * 3 * SS + 2 * SS + s] = cz;
        float qn = __fadd_rn(__fadd_rn(__fmul_rn(cx, cx), __fmul_rn(cy, cy)),
                             __fmul_rn(cz, cz));
        qpts[(long)b * SS + s] = make_float4(cx, cy, cz, qn);
    }
}

// ---------------------------------------------------------------------------
// Kernel 4 (FUSED knn+mlp): R12 structure, with the LDS footprint cut from
// 33920 B to exactly 32768 B so occupancy rises 4 -> 5 blocks/CU (was 1
// wave/SIMD, fully latency-exposed):
//  - the pad-skew (p + p>>5) is replaced by an in-place XOR swizzle
//    p ^ ((p>>6)&31). On the column rescan (stride 64 words) bank =
//    (own&31)^(l&31) -> every bank hit exactly 2x (free); phase-1 row
//    writes stay a within-row permutation (2-way, free). Zero pad bytes.
//  - sidxs overlaps dead dk words 2176..2207 (grouped uses 0..2175).
// All logical indices / compare order / fp ops unchanged -> bit-exact.
// ---------------------------------------------------------------------------
#define SWZ(p) ((p) ^ (((p) >> 6) & 31))
__global__ __launch_bounds__(64, 1) void k_knn_mlp(const float4* __restrict__ pts4,
                                                   const float* __restrict__ feaT,
                                                   const float4* __restrict__ qpts,
                                                   const float* __restrict__ W,
                                                   float* __restrict__ out) {
    __shared__ __align__(16) unsigned dk[NN];   // 32768 B exactly
    int* sidxs = (int*)(dk + 2176);     // 32 ints, dead-dk overlap
    float* grouped = (float*)dk;        // reused after pops: 32*68 floats (8704 B)

    int Q = blockIdx.x;                      // b*1024 + s
    int b = Q >> 10, s = Q & 1023;
    int l = threadIdx.x;
    float4 q = qpts[Q];
    const float4* P = pts4 + (long)b * NN;

    // ---- Phase 1: distance scan ----
    unsigned bmin = 0xFFFFFFFFu;
    int bpos = 0;
#pragma unroll 16
    for (int j = 0; j < 128; j++) {
        int p = j * 64 + l;
        float4 v = P[p];
        float dot = __fadd_rn(__fadd_rn(__fmul_rn(q.x, v.x), __fmul_rn(q.y, v.y)),
                              __fmul_rn(q.z, v.z));
        float d = __fadd_rn(__fsub_rn(q.w, __fmul_rn(2.0f, dot)), v.w);
        unsigned u = sortable(d);
        dk[SWZ(p)] = u;
        if (u < bmin) { bmin = u; bpos = p; }   // ascending p -> earliest index on tie
    }
    __syncthreads();

    // ---- Phase 2: W rows into registers, interleaved (latency overlaps pops) ----
    v2f wab[68];
    {
        const float* Wr = W + l * 67;
#pragma unroll
        for (int c = 0; c < 67; c++) {
            wab[c] = v2f{Wr[c], Wr[64 * 67 + c]};
        }
        wab[67] = v2f{0.f, 0.f};
    }

    // ---- Phase 3: 32 pops ----
    unsigned resv = 0;
    int resp = 0, pos0 = 0;
    for (int k = 0; k < GG; k++) {
        unsigned mv = bmin;
        mv = dpp_minu<0x111, 0xF>(mv);
        mv = dpp_minu<0x112, 0xF>(mv);
        mv = dpp_minu<0x114, 0xF>(mv);
        mv = dpp_minu<0x118, 0xF>(mv);
        mv = dpp_minu<0x142, 0xA>(mv);
        mv = dpp_minu<0x143, 0xC>(mv);
        unsigned wmin = (unsigned)__builtin_amdgcn_readlane((int)mv, 63);
        unsigned long long mask = __ballot(bmin == wmin);
        int wpos;
        if (__builtin_popcountll(mask) == 1) {
            int owner = __builtin_ctzll(mask);
            wpos = __builtin_amdgcn_readlane(bpos, owner);
        } else {
            unsigned long long kk =
                ((unsigned long long)bmin << 32) | (unsigned)bpos;
#pragma unroll
            for (int m = 1; m < 64; m <<= 1) {
                unsigned long long o = __shfl_xor(kk, m, 64);
                kk = (o < kk) ? o : kk;
            }
            wpos = (int)(kk & 0xFFFFFFFFull);
        }
        if (k == 0) pos0 = wpos;
        if (l == k) { resv = wmin; resp = wpos; }
        int own = wpos & 63;
        if (l == own) dk[SWZ(wpos)] = 0xFFFFFFFFu;   // invalidate popped slot
        __syncthreads();
        // cooperative rescan of owner's column (its 128 points)
        int p1 = l * 64 + own;
        int p2 = (l + 64) * 64 + own;
        unsigned v1 = dk[SWZ(p1)], v2 = dk[SWZ(p2)];
        bool c = v2 < v1;                 // p1 < p2, so tie keeps earliest
        unsigned cv = c ? v2 : v1;
        int cp = c ? p2 : p1;
        unsigned cm = cv;
        cm = dpp_minu<0x111, 0xF>(cm);
        cm = dpp_minu<0x112, 0xF>(cm);
        cm = dpp_minu<0x114, 0xF>(cm);
        cm = dpp_minu<0x118, 0xF>(cm);
        cm = dpp_minu<0x142, 0xA>(cm);
        cm = dpp_minu<0x143, 0xC>(cm);
        unsigned colmin = (unsigned)__builtin_amdgcn_readlane((int)cm, 63);
        unsigned long long m2 = __ballot(cv == colmin);
        int colpos;
        if (__builtin_popcountll(m2) == 1) {
            colpos = __builtin_amdgcn_readlane(cp, __builtin_ctzll(m2));
        } else {
            unsigned long long kk =
                ((unsigned long long)cv << 32) | (unsigned)cp;
#pragma unroll
            for (int m = 1; m < 64; m <<= 1) {
                unsigned long long o = __shfl_xor(kk, m, 64);
                kk = (o < kk) ? o : kk;
            }
            colpos = (int)(kk & 0xFFFFFFFFull);
        }
        if (l == own) { bmin = colmin; bpos = colpos; }
        __syncthreads();
    }

    // ---- Phase 4: final indices + gather into reused LDS ----
    if (l < GG) sidxs[l] = (resv > SORT_R2) ? pos0 : resp;   // radius filter
    __syncthreads();   // sidxs visible; dk keys dead from here on

    if (l < 32) {
        int idx = sidxs[l];
        float4 p = pts4[(long)b * NN + idx];
        float4 rc = make_float4(__fsub_rn(p.x, q.x), __fsub_rn(p.y, q.y),
                                __fsub_rn(p.z, q.z), 0.f);
        *(float4*)&grouped[l * 68 + 64] = rc;
    }
    {
        int g = l >> 1, half = l & 1;
        int idx = sidxs[g];
        const float4* f4 = (const float4*)(feaT + ((long)b * NN + idx) * 64);
#pragma unroll
        for (int k4 = 0; k4 < 8; k4++) {
            *(float4*)&grouped[g * 68 + half * 32 + k4 * 4] = f4[half * 8 + k4];
        }
    }
    __syncthreads();

    // ---- Phase 5: 1x1 conv + relu + max over group (packed pk_fma) ----
    v2f mm = v2f{-1e30f, -1e30f};
#pragma unroll 2
    for (int g = 0; g < GG; g++) {
        v2f a = v2f{0.f, 0.f};
#pragma unroll
        for (int c4 = 0; c4 < 17; c4++) {
            float4 gv = *(float4*)&grouped[g * 68 + c4 * 4];
            a = __builtin_elementwise_fma(v2f{gv.x, gv.x}, wab[4 * c4 + 0], a);
            a = __builtin_elementwise_fma(v2f{gv.y, gv.y}, wab[4 * c4 + 1], a);
            a = __builtin_elementwise_fma(v2f{gv.z, gv.z}, wab[4 * c4 + 2], a);
            a = __builtin_elementwise_fma(v2f{gv.w, gv.w}, wab[4 * c4 + 3], a);
        }
        mm = __builtin_elementwise_max(mm, a);
    }
    // outputs: (B,3,S) then (B,128,S); relu(max) == max(relu)
    out[49152 + ((long)b * 128 + l) * SS + s]      = fmaxf(mm.x, 0.f);
    out[49152 + ((long)b * 128 + l + 64) * SS + s] = fmaxf(mm.y, 0.f);
}

// ---------------------------------------------------------------------------
extern "C" void kernel_launch(void* const* d_in, const int* in_sizes, int n_in,
                              void* d_out, int out_size, void* d_ws, size_t ws_size,
                              hipStream_t stream) {
    const float* coor = (const float*)d_in[0];   // (16,3,8192)
    const float* fea  = (const float*)d_in[1];   // (16,64,8192)
    const float* Wm   = (const float*)d_in[2];   // (128,67)
    float* out = (float*)d_out;

    char* ws = (char*)d_ws;
    float4* pts4 = (float4*)ws;                               //  2 MB
    float*  feaT = (float*)(ws + 2097152);                    // 32 MB
    float4* qpts = (float4*)(ws + 2097152 + 33554432);        // 256 KB

    k_pts<<<(BB * NN) / 256, 256, 0, stream>>>(coor, pts4);
    k_tr<<<dim3(NN / 64, BB), 256, 0, stream>>>(fea, feaT);
    k_fps<<<BB, 512, 0, stream>>>(pts4, qpts, out);
    k_knn_mlp<<<BB * SS, 64, 0, stream>>>(pts4, feaT, qpts, Wm, out);
}

// Round 5
// 1432.196 us; speedup vs baseline: 1.6174x; 1.0252x over previous
//
#include <hip/hip_runtime.h>
#include <hip/hip_bf16.h>

// Problem constants
#define BB 16
#define NN 8192
#define SS 1024
#define GG 32
// sortable(1.0f) = 0x3F800000 ^ 0x80000000
#define SORT_R2 0xBF800000u

typedef float v2f __attribute__((ext_vector_type(2)));

__device__ __forceinline__ unsigned sortable(float f) {
    unsigned u = __float_as_uint(f);
    return u ^ ((unsigned)(((int)u) >> 31) | 0x80000000u);
}

// f32 max-combine with a DPP-permuted copy (2 slots: v_mov_dpp + v_max_f32).
// row_shr:n = 0x110|n, row_bcast15 = 0x142, row_bcast31 = 0x143.
template <int CTRL, int RM>
__device__ __forceinline__ float dpp_maxf(float v) {
    int i = __float_as_int(v);
    int p = __builtin_amdgcn_update_dpp(i, i, CTRL, RM, 0xF, false);
    return fmaxf(v, __int_as_float(p));
}

// u32 min-combine with a DPP-permuted copy (2 slots).
template <int CTRL, int RM>
__device__ __forceinline__ unsigned dpp_minu(unsigned v) {
    int p = __builtin_amdgcn_update_dpp((int)v, (int)v, CTRL, RM, 0xF, false);
    return min(v, (unsigned)p);
}

__device__ __forceinline__ float fmax3(float a, float b, float c) {
    return fmaxf(fmaxf(a, b), c);   // fuses to v_max3_f32
}

// ---------------------------------------------------------------------------
// Kernel 1: pack pts4[b][n] = {x, y, z, (x*x+y*y)+z*z}  (rn ops, no contraction)
// ---------------------------------------------------------------------------
__global__ __launch_bounds__(256) void k_pts(const float* __restrict__ coor,
                                             float4* __restrict__ pts4) {
    int i = blockIdx.x * 256 + threadIdx.x;   // 0 .. B*N-1
    int b = i >> 13, n = i & (NN - 1);
    const float* cb = coor + (long)b * 3 * NN;
    float x = cb[n], y = cb[NN + n], z = cb[2 * NN + n];
    float pn = __fadd_rn(__fadd_rn(__fmul_rn(x, x), __fmul_rn(y, y)), __fmul_rn(z, z));
    pts4[i] = make_float4(x, y, z, pn);
}

// ---------------------------------------------------------------------------
// Kernel 2: transpose fea (B,64,N) -> feaT (B,N,64)
// ---------------------------------------------------------------------------
__global__ __launch_bounds__(256) void k_tr(const float* __restrict__ fea,
                                            float* __restrict__ feaT) {
    __shared__ float tile[64][65];
    int b = blockIdx.y, n0 = blockIdx.x * 64;
    int t = threadIdx.x;
    int nl = t & 63, cb = t >> 6;
#pragma unroll
    for (int i = 0; i < 16; i++) {
        int c = cb * 16 + i;
        tile[nl][c] = fea[((long)b * 64 + c) * NN + n0 + nl];
    }
    __syncthreads();
    int cl = t & 63, nb = t >> 6;
#pragma unroll
    for (int i = 0; i < 16; i++) {
        int n = nb * 16 + i;
        feaT[((long)b * NN + n0 + n) * 64 + cl] = tile[n][cl];
    }
}

// ---------------------------------------------------------------------------
// Kernel 3: farthest point sampling. One block (512 thr) per batch.
// R12 verbatim (measured optimum ~935 us). Six structural attacks
// (issue-count, barrier-count, 2x wave-count, Morton+skip, 2-wave/VGPR-
// spill) all regressed; 512 thr / 2 waves-per-SIMD is the floor config.
// ---------------------------------------------------------------------------
__global__ __launch_bounds__(512) void k_fps(const float4* __restrict__ pts4,
                                             float4* __restrict__ qpts,
                                             float* __restrict__ out) {
#pragma clang fp contract(off)
    __shared__ float xs[NN], ys[NN], zs[NN];
    __shared__ int scur[SS];
    __shared__ __align__(16) float redv[2][8];
    __shared__ int sidx[2];
    int b = blockIdx.x;
    int t = threadIdx.x;
    const float4* P = pts4 + (long)b * NN;

    // pair j, half h -> point p = t + (2j+h)*512
    v2f px[8], py[8], pz[8], dist[8];
#pragma unroll
    for (int j = 0; j < 8; j++) {
        int p0 = t + (2 * j) * 512;
        int p1 = t + (2 * j + 1) * 512;
        float4 a = P[p0];
        float4 c = P[p1];
        px[j] = v2f{a.x, c.x};
        py[j] = v2f{a.y, c.y};
        pz[j] = v2f{a.z, c.z};
        dist[j] = v2f{1e10f, 1e10f};
        xs[p0] = a.x; ys[p0] = a.y; zs[p0] = a.z;
        xs[p1] = c.x; ys[p1] = c.y; zs[p1] = c.z;
    }
    if (t == 0) { sidx[0] = 0x7FFFFFFF; sidx[1] = 0x7FFFFFFF; }
    __syncthreads();

    int cur = 0;
    for (int s = 0; s < SS; s++) {
        int par = s & 1;
        float cx = xs[cur], cy = ys[cur], cz = zs[cur];
        if (t == 0) scur[s] = cur;
        v2f cx2 = v2f{cx, cx}, cy2 = v2f{cy, cy}, cz2 = v2f{cz, cz};
#pragma unroll
        for (int j = 0; j < 8; j++) {
            v2f dx = px[j] - cx2;
            v2f dy = py[j] - cy2;
            v2f dz = pz[j] - cz2;
            v2f xx = dx * dx;
            v2f yy = dy * dy;
            v2f zz = dz * dz;
            v2f sm = xx + yy;
            v2f d = sm + zz;
            dist[j] = __builtin_elementwise_min(dist[j], d);
        }
        // value-only per-thread max: packed tree (7 pk-max) + final scalar
        v2f m01 = __builtin_elementwise_max(dist[0], dist[1]);
        v2f m23 = __builtin_elementwise_max(dist[2], dist[3]);
        v2f m45 = __builtin_elementwise_max(dist[4], dist[5]);
        v2f m67 = __builtin_elementwise_max(dist[6], dist[7]);
        v2f m03 = __builtin_elementwise_max(m01, m23);
        v2f m47 = __builtin_elementwise_max(m45, m67);
        v2f m07 = __builtin_elementwise_max(m03, m47);
        float bv = fmaxf(m07.x, m07.y);
        // 64-lane DPP f32 max; full-wave max lands in lane 63
        float wv = bv;
        wv = dpp_maxf<0x111, 0xF>(wv);   // row_shr:1
        wv = dpp_maxf<0x112, 0xF>(wv);   // row_shr:2
        wv = dpp_maxf<0x114, 0xF>(wv);   // row_shr:4
        wv = dpp_maxf<0x118, 0xF>(wv);   // row_shr:8
        wv = dpp_maxf<0x142, 0xA>(wv);   // row_bcast:15 (rows 1,3)
        wv = dpp_maxf<0x143, 0xC>(wv);   // row_bcast:31 (rows 2,3)
        if ((t & 63) == 63) redv[par][t >> 6] = wv;
        __syncthreads();                 // barrier 1
        float4 r0 = *(const float4*)redv[par];
        float4 r1 = *(const float4*)(redv[par] + 4);
        float gmax = fmaxf(fmax3(r0.x, r0.y, r0.z),
                           fmax3(r0.w, fmax3(r1.x, r1.y, r1.z), r1.w));
        // reset the OTHER sidx slot (used at s+1); barrier 2 separates it
        // from s+1's atomics.
        if (t == 0) sidx[1 - par] = 0x7FFFFFFF;
        if (bv == gmax) {
            // block-rare path (usually 1 thread): lowest matching ord
            int jj = 16;
#pragma unroll
            for (int j = 7; j >= 0; j--) {
                jj = (dist[j].y == gmax) ? (2 * j + 1) : jj;
                jj = (dist[j].x == gmax) ? (2 * j) : jj;
            }
            atomicMin(&sidx[par], t + jj * 512);
        }
        __syncthreads();                 // barrier 2
        cur = sidx[par];
    }
    __syncthreads();

    // epilogue: write new_coor (B,3,S) and query points from recorded indices
#pragma unroll
    for (int s = t; s < SS; s += 512) {
        int c = scur[s];
        float cx = xs[c], cy = ys[c], cz = zs[c];
        out[(long)b * 3 * SS + s]          = cx;
        out[(long)b * 3 * SS + SS + s]     = cy;
        out[(long)b * 3 * SS + 2 * SS + s] = cz;
        float qn = __fadd_rn(__fadd_rn(__fmul_rn(cx, cx), __fmul_rn(cy, cy)),
                             __fmul_rn(cz, cz));
        qpts[(long)b * SS + s] = make_float4(cx, cy, cz, qn);
    }
}

// ---------------------------------------------------------------------------
// Kernel 4 (FUSED knn+mlp). R15: per-lane TOP-2 QUEUES kill the pop loop's
// serial latency. Phase 1 keeps each lane's two smallest (u,pos) in
// registers (sorted insert; head == old bmin exactly). A pop is now just:
// DPP wave-min over heads -> readlane -> owner promotes its 2nd entry.
// No LDS read, no rescan, no barrier in the common path (~200 cy vs
// ~500-600 cy). dk remains ground truth: consumed slots are invalidated,
// and when a lane's queue empties (3rd+ pop from one lane, ~1 event/block)
// the old cooperative column-rescan refills it — so any entry dropped from
// the 2-deep queue is recoverable and the pop sequence is IDENTICAL to the
// global iterative pop (lane head is always the true min of its
// un-consumed column; tie-break by lowest pos unchanged) -> bit-exact.
// LDS stays 32768 B (5 blocks/CU); sidxs overlaps dead dk words.
// ---------------------------------------------------------------------------
#define SWZ(p) ((p) ^ (((p) >> 6) & 31))
__global__ __launch_bounds__(64, 1) void k_knn_mlp(const float4* __restrict__ pts4,
                                                   const float* __restrict__ feaT,
                                                   const float4* __restrict__ qpts,
                                                   const float* __restrict__ W,
                                                   float* __restrict__ out) {
    __shared__ __align__(16) unsigned dk[NN];   // 32768 B exactly
    int* sidxs = (int*)(dk + 2176);     // 32 ints, dead-dk overlap
    float* grouped = (float*)dk;        // reused after pops: 32*68 floats (8704 B)

    int Q = blockIdx.x;                      // b*1024 + s
    int b = Q >> 10, s = Q & 1023;
    int l = threadIdx.x;
    float4 q = qpts[Q];
    const float4* P = pts4 + (long)b * NN;

    // ---- Phase 1: distance scan + per-lane top-2 (u0,p0)<(u1q,p1q) ----
    unsigned u0 = 0xFFFFFFFFu, u1q = 0xFFFFFFFFu;
    int p0 = 0, p1q = 0;
#pragma unroll 16
    for (int j = 0; j < 128; j++) {
        int p = j * 64 + l;
        float4 v = P[p];
        float dot = __fadd_rn(__fadd_rn(__fmul_rn(q.x, v.x), __fmul_rn(q.y, v.y)),
                              __fmul_rn(q.z, v.z));
        float d = __fadd_rn(__fsub_rn(q.w, __fmul_rn(2.0f, dot)), v.w);
        unsigned u = sortable(d);
        dk[SWZ(p)] = u;
        // sorted insert, ascending p scan; strict < keeps earliest pos on ties
        bool c0 = u < u0;
        bool c1 = u < u1q;
        u1q = c1 ? (c0 ? u0 : u) : u1q;
        p1q = c1 ? (c0 ? p0 : p) : p1q;
        u0 = c0 ? u : u0;
        p0 = c0 ? p : p0;
    }
    __syncthreads();

    // ---- Phase 2: W rows into registers, interleaved (latency overlaps pops) ----
    v2f wab[68];
    {
        const float* Wr = W + l * 67;
#pragma unroll
        for (int c = 0; c < 67; c++) {
            wab[c] = v2f{Wr[c], Wr[64 * 67 + c]};
        }
        wab[67] = v2f{0.f, 0.f};
    }

    // ---- Phase 3: 32 pops (queue common path; rare dk rescan on empty) ----
    unsigned resv = 0;
    int resp = 0, pos0 = 0;
    for (int k = 0; k < GG; k++) {
        unsigned mv = u0;
        mv = dpp_minu<0x111, 0xF>(mv);
        mv = dpp_minu<0x112, 0xF>(mv);
        mv = dpp_minu<0x114, 0xF>(mv);
        mv = dpp_minu<0x118, 0xF>(mv);
        mv = dpp_minu<0x142, 0xA>(mv);
        mv = dpp_minu<0x143, 0xC>(mv);
        unsigned wmin = (unsigned)__builtin_amdgcn_readlane((int)mv, 63);
        unsigned long long mask = __ballot(u0 == wmin);
        int wpos;
        if (__builtin_popcountll(mask) == 1) {
            int owner = __builtin_ctzll(mask);
            wpos = __builtin_amdgcn_readlane(p0, owner);
        } else {
            unsigned long long kk =
                ((unsigned long long)u0 << 32) | (unsigned)p0;
#pragma unroll
            for (int m = 1; m < 64; m <<= 1) {
                unsigned long long o = __shfl_xor(kk, m, 64);
                kk = (o < kk) ? o : kk;
            }
            wpos = (int)(kk & 0xFFFFFFFFull);
        }
        if (k == 0) pos0 = wpos;
        if (l == k) { resv = wmin; resp = wpos; }
        int own = wpos & 63;                   // p = j*64 + lane
        if (l == own) {
            dk[SWZ(wpos)] = 0xFFFFFFFFu;       // consume: ground-truth invalidate
            u0 = u1q; p0 = p1q;                // promote 2nd -> head
            u1q = 0xFFFFFFFFu;
        }
        // owner's new head (0xFFFFFFFF unreachable for finite distances)
        unsigned oh = (unsigned)__builtin_amdgcn_readlane((int)u0, own);
        if (oh == 0xFFFFFFFFu) {
            // RARE: owner queue empty -> cooperative refill from dk
            __syncthreads();   // order prior invalidate writes before reads
            int rc1 = l * 64 + own;
            int rc2 = (l + 64) * 64 + own;
            unsigned v1 = dk[SWZ(rc1)], v2 = dk[SWZ(rc2)];
            bool c = v2 < v1;                 // rc1 < rc2, tie keeps earliest
            unsigned cv = c ? v2 : v1;
            int cp = c ? rc2 : rc1;
            unsigned cm = cv;
            cm = dpp_minu<0x111, 0xF>(cm);
            cm = dpp_minu<0x112, 0xF>(cm);
            cm = dpp_minu<0x114, 0xF>(cm);
            cm = dpp_minu<0x118, 0xF>(cm);
            cm = dpp_minu<0x142, 0xA>(cm);
            cm = dpp_minu<0x143, 0xC>(cm);
            unsigned colmin = (unsigned)__builtin_amdgcn_readlane((int)cm, 63);
            unsigned long long m2 = __ballot(cv == colmin);
            int colpos;
            if (__builtin_popcountll(m2) == 1) {
                colpos = __builtin_amdgcn_readlane(cp, __builtin_ctzll(m2));
            } else {
                unsigned long long kk =
                    ((unsigned long long)cv << 32) | (unsigned)cp;
#pragma unroll
                for (int m = 1; m < 64; m <<= 1) {
                    unsigned long long o = __shfl_xor(kk, m, 64);
                    kk = (o < kk) ? o : kk;
                }
                colpos = (int)(kk & 0xFFFFFFFFull);
            }
            if (l == own) { u0 = colmin; p0 = colpos; }
        }
    }

    // ---- Phase 4: final indices + gather into reused LDS ----
    if (l < GG) sidxs[l] = (resv > SORT_R2) ? pos0 : resp;   // radius filter
    __syncthreads();   // sidxs visible; dk keys dead from here on

    if (l < 32) {
        int idx = sidxs[l];
        float4 p = pts4[(long)b * NN + idx];
        float4 rc = make_float4(__fsub_rn(p.x, q.x), __fsub_rn(p.y, q.y),
                                __fsub_rn(p.z, q.z), 0.f);
        *(float4*)&grouped[l * 68 + 64] = rc;
    }
    {
        int g = l >> 1, half = l & 1;
        int idx = sidxs[g];
        const float4* f4 = (const float4*)(feaT + ((long)b * NN + idx) * 64);
#pragma unroll
        for (int k4 = 0; k4 < 8; k4++) {
            *(float4*)&grouped[g * 68 + half * 32 + k4 * 4] = f4[half * 8 + k4];
        }
    }
    __syncthreads();

    // ---- Phase 5: 1x1 conv + relu + max over group (packed pk_fma) ----
    v2f mm = v2f{-1e30f, -1e30f};
#pragma unroll 2
    for (int g = 0; g < GG; g++) {
        v2f a = v2f{0.f, 0.f};
#pragma unroll
        for (int c4 = 0; c4 < 17; c4++) {
            float4 gv = *(float4*)&grouped[g * 68 + c4 * 4];
            a = __builtin_elementwise_fma(v2f{gv.x, gv.x}, wab[4 * c4 + 0], a);
            a = __builtin_elementwise_fma(v2f{gv.y, gv.y}, wab[4 * c4 + 1], a);
            a = __builtin_elementwise_fma(v2f{gv.z, gv.z}, wab[4 * c4 + 2], a);
            a = __builtin_elementwise_fma(v2f{gv.w, gv.w}, wab[4 * c4 + 3], a);
        }
        mm = __builtin_elementwise_max(mm, a);
    }
    // outputs: (B,3,S) then (B,128,S); relu(max) == max(relu)
    out[49152 + ((long)b * 128 + l) * SS + s]      = fmaxf(mm.x, 0.f);
    out[49152 + ((long)b * 128 + l + 64) * SS + s] = fmaxf(mm.y, 0.f);
}

// ---------------------------------------------------------------------------
extern "C" void kernel_launch(void* const* d_in, const int* in_sizes, int n_in,
                              void* d_out, int out_size, void* d_ws, size_t ws_size,
                              hipStream_t stream) {
    const float* coor = (const float*)d_in[0];   // (16,3,8192)
    const float* fea  = (const float*)d_in[1];   // (16,64,8192)
    const float* Wm   = (const float*)d_in[2];   // (128,67)
    float* out = (float*)d_out;

    char* ws = (char*)d_ws;
    float4* pts4 = (float4*)ws;                               //  2 MB
    float*  feaT = (float*)(ws + 2097152);                    // 32 MB
    float4* qpts = (float4*)(ws + 2097152 + 33554432);        // 256 KB

    k_pts<<<(BB * NN) / 256, 256, 0, stream>>>(coor, pts4);
    k_tr<<<dim3(NN / 64, BB), 256, 0, stream>>>(fea, feaT);
    k_fps<<<BB, 512, 0, stream>>>(pts4, qpts, out);
    k_knn_mlp<<<BB * SS, 64, 0, stream>>>(pts4, feaT, qpts, Wm, out);
}

// Round 7
// 1269.582 us; speedup vs baseline: 1.8246x; 1.1281x over previous
//
#include <hip/hip_runtime.h>
#include <hip/hip_bf16.h>

// Problem constants
#define BB 16
#define NN 8192
#define SS 1024
#define GG 32
// sortable(1.0f) = 0x3F800000 ^ 0x80000000
#define SORT_R2 0xBF800000u

typedef float v2f __attribute__((ext_vector_type(2)));

__device__ __forceinline__ unsigned sortable(float f) {
    unsigned u = __float_as_uint(f);
    return u ^ ((unsigned)(((int)u) >> 31) | 0x80000000u);
}

// f32 max-combine with a DPP-permuted copy (2 slots: v_mov_dpp + v_max_f32).
// row_shr:n = 0x110|n, row_bcast15 = 0x142, row_bcast31 = 0x143.
template <int CTRL, int RM>
__device__ __forceinline__ float dpp_maxf(float v) {
    int i = __float_as_int(v);
    int p = __builtin_amdgcn_update_dpp(i, i, CTRL, RM, 0xF, false);
    return fmaxf(v, __int_as_float(p));
}

// u32 min-combine with a DPP-permuted copy (2 slots).
template <int CTRL, int RM>
__device__ __forceinline__ unsigned dpp_minu(unsigned v) {
    int p = __builtin_amdgcn_update_dpp((int)v, (int)v, CTRL, RM, 0xF, false);
    return min(v, (unsigned)p);
}

__device__ __forceinline__ float fmax3(float a, float b, float c) {
    return fmaxf(fmaxf(a, b), c);   // fuses to v_max3_f32
}

// ---------------------------------------------------------------------------
// Kernel 1: pack pts4[b][n] = {x, y, z, (x*x+y*y)+z*z}  (rn ops, no contraction)
// ---------------------------------------------------------------------------
__global__ __launch_bounds__(256) void k_pts(const float* __restrict__ coor,
                                             float4* __restrict__ pts4) {
    int i = blockIdx.x * 256 + threadIdx.x;   // 0 .. B*N-1
    int b = i >> 13, n = i & (NN - 1);
    const float* cb = coor + (long)b * 3 * NN;
    float x = cb[n], y = cb[NN + n], z = cb[2 * NN + n];
    float pn = __fadd_rn(__fadd_rn(__fmul_rn(x, x), __fmul_rn(y, y)), __fmul_rn(z, z));
    pts4[i] = make_float4(x, y, z, pn);
}

// ---------------------------------------------------------------------------
// Kernel 2: transpose fea (B,64,N) -> feaT (B,N,64)
// ---------------------------------------------------------------------------
__global__ __launch_bounds__(256) void k_tr(const float* __restrict__ fea,
                                            float* __restrict__ feaT) {
    __shared__ float tile[64][65];
    int b = blockIdx.y, n0 = blockIdx.x * 64;
    int t = threadIdx.x;
    int nl = t & 63, cb = t >> 6;
#pragma unroll
    for (int i = 0; i < 16; i++) {
        int c = cb * 16 + i;
        tile[nl][c] = fea[((long)b * 64 + c) * NN + n0 + nl];
    }
    __syncthreads();
    int cl = t & 63, nb = t >> 6;
#pragma unroll
    for (int i = 0; i < 16; i++) {
        int n = nb * 16 + i;
        feaT[((long)b * NN + n0 + n) * 64 + cl] = tile[n][cl];
    }
}

// ---------------------------------------------------------------------------
// Kernel 3: farthest point sampling. One block (512 thr) per batch.
// R12 verbatim (measured optimum ~935 us). Six structural attacks
// (issue-count, barrier-count, 2x wave-count, Morton+skip, 2-wave/VGPR-
// spill) all regressed; 512 thr / 2 waves-per-SIMD is the floor config.
// ---------------------------------------------------------------------------
__global__ __launch_bounds__(512) void k_fps(const float4* __restrict__ pts4,
                                             float4* __restrict__ qpts,
                                             float* __restrict__ out) {
#pragma clang fp contract(off)
    __shared__ float xs[NN], ys[NN], zs[NN];
    __shared__ int scur[SS];
    __shared__ __align__(16) float redv[2][8];
    __shared__ int sidx[2];
    int b = blockIdx.x;
    int t = threadIdx.x;
    const float4* P = pts4 + (long)b * NN;

    // pair j, half h -> point p = t + (2j+h)*512
    v2f px[8], py[8], pz[8], dist[8];
#pragma unroll
    for (int j = 0; j < 8; j++) {
        int p0 = t + (2 * j) * 512;
        int p1 = t + (2 * j + 1) * 512;
        float4 a = P[p0];
        float4 c = P[p1];
        px[j] = v2f{a.x, c.x};
        py[j] = v2f{a.y, c.y};
        pz[j] = v2f{a.z, c.z};
        dist[j] = v2f{1e10f, 1e10f};
        xs[p0] = a.x; ys[p0] = a.y; zs[p0] = a.z;
        xs[p1] = c.x; ys[p1] = c.y; zs[p1] = c.z;
    }
    if (t == 0) { sidx[0] = 0x7FFFFFFF; sidx[1] = 0x7FFFFFFF; }
    __syncthreads();

    int cur = 0;
    for (int s = 0; s < SS; s++) {
        int par = s & 1;
        float cx = xs[cur], cy = ys[cur], cz = zs[cur];
        if (t == 0) scur[s] = cur;
        v2f cx2 = v2f{cx, cx}, cy2 = v2f{cy, cy}, cz2 = v2f{cz, cz};
#pragma unroll
        for (int j = 0; j < 8; j++) {
            v2f dx = px[j] - cx2;
            v2f dy = py[j] - cy2;
            v2f dz = pz[j] - cz2;
            v2f xx = dx * dx;
            v2f yy = dy * dy;
            v2f zz = dz * dz;
            v2f sm = xx + yy;
            v2f d = sm + zz;
            dist[j] = __builtin_elementwise_min(dist[j], d);
        }
        // value-only per-thread max: packed tree (7 pk-max) + final scalar
        v2f m01 = __builtin_elementwise_max(dist[0], dist[1]);
        v2f m23 = __builtin_elementwise_max(dist[2], dist[3]);
        v2f m45 = __builtin_elementwise_max(dist[4], dist[5]);
        v2f m67 = __builtin_elementwise_max(dist[6], dist[7]);
        v2f m03 = __builtin_elementwise_max(m01, m23);
        v2f m47 = __builtin_elementwise_max(m45, m67);
        v2f m07 = __builtin_elementwise_max(m03, m47);
        float bv = fmaxf(m07.x, m07.y);
        // 64-lane DPP f32 max; full-wave max lands in lane 63
        float wv = bv;
        wv = dpp_maxf<0x111, 0xF>(wv);   // row_shr:1
        wv = dpp_maxf<0x112, 0xF>(wv);   // row_shr:2
        wv = dpp_maxf<0x114, 0xF>(wv);   // row_shr:4
        wv = dpp_maxf<0x118, 0xF>(wv);   // row_shr:8
        wv = dpp_maxf<0x142, 0xA>(wv);   // row_bcast:15 (rows 1,3)
        wv = dpp_maxf<0x143, 0xC>(wv);   // row_bcast:31 (rows 2,3)
        if ((t & 63) == 63) redv[par][t >> 6] = wv;
        __syncthreads();                 // barrier 1
        float4 r0 = *(const float4*)redv[par];
        float4 r1 = *(const float4*)(redv[par] + 4);
        float gmax = fmaxf(fmax3(r0.x, r0.y, r0.z),
                           fmax3(r0.w, fmax3(r1.x, r1.y, r1.z), r1.w));
        // reset the OTHER sidx slot (used at s+1); barrier 2 separates it
        // from s+1's atomics.
        if (t == 0) sidx[1 - par] = 0x7FFFFFFF;
        if (bv == gmax) {
            // block-rare path (usually 1 thread): lowest matching ord
            int jj = 16;
#pragma unroll
            for (int j = 7; j >= 0; j--) {
                jj = (dist[j].y == gmax) ? (2 * j + 1) : jj;
                jj = (dist[j].x == gmax) ? (2 * j) : jj;
            }
            atomicMin(&sidx[par], t + jj * 512);
        }
        __syncthreads();                 // barrier 2
        cur = sidx[par];
    }
    __syncthreads();

    // epilogue: write new_coor (B,3,S) and query points from recorded indices
#pragma unroll
    for (int s = t; s < SS; s += 512) {
        int c = scur[s];
        float cx = xs[c], cy = ys[c], cz = zs[c];
        out[(long)b * 3 * SS + s]          = cx;
        out[(long)b * 3 * SS + SS + s]     = cy;
        out[(long)b * 3 * SS + 2 * SS + s] = cz;
        float qn = __fadd_rn(__fadd_rn(__fmul_rn(cx, cx), __fmul_rn(cy, cy)),
                             __fmul_rn(cz, cz));
        qpts[(long)b * SS + s] = make_float4(cx, cy, cz, qn);
    }
}

// ---------------------------------------------------------------------------
// Kernel 4 (FUSED knn+mlp). R16: dk ELIMINATED -> LDS 32768 B -> 8832 B.
// R15's top-2 queues made the 32KB key array redundant except for the rare
// queue-empty refill (~1 event/block). That fallback is now a RECOMPUTE:
// each lane tracks its own column's consumed positions in a 128-bit reg
// mask; on refill all lanes re-load the owner's 128 points from pts4
// (L2-hot) and recompute distances with the identical rn-op formula
// (IEEE-deterministic -> identical u bits), masking consumed slots. Pop
// semantics unchanged (lane head = true min of its unconsumed column;
// all tie-breaks identical) -> bit-exact. Occupancy: 5 blocks/CU
// (LDS-bound) -> ~12 (VGPR-bound, ~3 waves/SIMD) for 2.4x latency hiding;
// phase 1 also loses all 128 LDS writes + swizzle address math.
// ---------------------------------------------------------------------------
__global__ __launch_bounds__(64, 1) void k_knn_mlp(const float4* __restrict__ pts4,
                                                   const float* __restrict__ feaT,
                                                   const float4* __restrict__ qpts,
                                                   const float* __restrict__ W,
                                                   float* __restrict__ out) {
    __shared__ __align__(16) float grouped[GG * 68];   // 8704 B
    __shared__ int sidxs[GG];                          //  128 B

    int Q = blockIdx.x;                      // b*1024 + s
    int b = Q >> 10, s = Q & 1023;
    int l = threadIdx.x;
    float4 q = qpts[Q];
    const float4* P = pts4 + (long)b * NN;

    // ---- Phase 1: distance scan + per-lane top-2 (u0,p0)<(u1q,p1q) ----
    unsigned u0 = 0xFFFFFFFFu, u1q = 0xFFFFFFFFu;
    int p0 = 0, p1q = 0;
#pragma unroll 16
    for (int j = 0; j < 128; j++) {
        int p = j * 64 + l;
        float4 v = P[p];
        float dot = __fadd_rn(__fadd_rn(__fmul_rn(q.x, v.x), __fmul_rn(q.y, v.y)),
                              __fmul_rn(q.z, v.z));
        float d = __fadd_rn(__fsub_rn(q.w, __fmul_rn(2.0f, dot)), v.w);
        unsigned u = sortable(d);
        // sorted insert, ascending p scan; strict < keeps earliest pos on ties
        bool c0 = u < u0;
        bool c1 = u < u1q;
        u1q = c1 ? (c0 ? u0 : u) : u1q;
        p1q = c1 ? (c0 ? p0 : p) : p1q;
        u0 = c0 ? u : u0;
        p0 = c0 ? p : p0;
    }

    // ---- Phase 2: W rows into registers (latency overlaps pops) ----
    v2f wab[68];
    {
        const float* Wr = W + l * 67;
#pragma unroll
        for (int c = 0; c < 67; c++) {
            wab[c] = v2f{Wr[c], Wr[64 * 67 + c]};
        }
        wab[67] = v2f{0.f, 0.f};
    }

    // ---- Phase 3: 32 pops (queue common path; rare recompute-refill) ----
    // consLo/consHi: bit j set <=> point j*64+l consumed (this lane's column)
    unsigned long long consLo = 0ull, consHi = 0ull;
    unsigned resv = 0;
    int resp = 0, pos0 = 0;
    for (int k = 0; k < GG; k++) {
        unsigned mv = u0;
        mv = dpp_minu<0x111, 0xF>(mv);
        mv = dpp_minu<0x112, 0xF>(mv);
        mv = dpp_minu<0x114, 0xF>(mv);
        mv = dpp_minu<0x118, 0xF>(mv);
        mv = dpp_minu<0x142, 0xA>(mv);
        mv = dpp_minu<0x143, 0xC>(mv);
        unsigned wmin = (unsigned)__builtin_amdgcn_readlane((int)mv, 63);
        unsigned long long mask = __ballot(u0 == wmin);
        int wpos;
        if (__builtin_popcountll(mask) == 1) {
            int owner = __builtin_ctzll(mask);
            wpos = __builtin_amdgcn_readlane(p0, owner);
        } else {
            unsigned long long kk =
                ((unsigned long long)u0 << 32) | (unsigned)p0;
#pragma unroll
            for (int m = 1; m < 64; m <<= 1) {
                unsigned long long o = __shfl_xor(kk, m, 64);
                kk = (o < kk) ? o : kk;
            }
            wpos = (int)(kk & 0xFFFFFFFFull);
        }
        if (k == 0) pos0 = wpos;
        if (l == k) { resv = wmin; resp = wpos; }
        int own = wpos & 63;                   // p = j*64 + lane
        if (l == own) {
            int jj = wpos >> 6;                // consumed column slot
            if (jj < 64) consLo |= 1ull << jj;
            else         consHi |= 1ull << (jj - 64);
            u0 = u1q; p0 = p1q;                // promote 2nd -> head
            u1q = 0xFFFFFFFFu;
        }
        // owner's new head (0xFFFFFFFF unreachable for finite distances)
        unsigned oh = (unsigned)__builtin_amdgcn_readlane((int)u0, own);
        if (oh == 0xFFFFFFFFu) {
            // RARE: owner queue empty -> cooperative recompute of its column
            unsigned long long mLo = __shfl(consLo, own, 64);
            unsigned long long mHi = __shfl(consHi, own, 64);
            int rc1 = l * 64 + own;
            int rc2 = (l + 64) * 64 + own;
            float4 a1 = P[rc1];
            float4 a2 = P[rc2];
            float dot1 = __fadd_rn(__fadd_rn(__fmul_rn(q.x, a1.x), __fmul_rn(q.y, a1.y)),
                                   __fmul_rn(q.z, a1.z));
            float d1 = __fadd_rn(__fsub_rn(q.w, __fmul_rn(2.0f, dot1)), a1.w);
            unsigned uu1 = sortable(d1);
            float dot2 = __fadd_rn(__fadd_rn(__fmul_rn(q.x, a2.x), __fmul_rn(q.y, a2.y)),
                                   __fmul_rn(q.z, a2.z));
            float d2 = __fadd_rn(__fsub_rn(q.w, __fmul_rn(2.0f, dot2)), a2.w);
            unsigned uu2 = sortable(d2);
            if ((mLo >> l) & 1) uu1 = 0xFFFFFFFFu;
            if ((mHi >> l) & 1) uu2 = 0xFFFFFFFFu;
            bool c = uu2 < uu1;               // rc1 < rc2, tie keeps earliest
            unsigned cv = c ? uu2 : uu1;
            int cp = c ? rc2 : rc1;
            unsigned cm = cv;
            cm = dpp_minu<0x111, 0xF>(cm);
            cm = dpp_minu<0x112, 0xF>(cm);
            cm = dpp_minu<0x114, 0xF>(cm);
            cm = dpp_minu<0x118, 0xF>(cm);
            cm = dpp_minu<0x142, 0xA>(cm);
            cm = dpp_minu<0x143, 0xC>(cm);
            unsigned colmin = (unsigned)__builtin_amdgcn_readlane((int)cm, 63);
            unsigned long long m2 = __ballot(cv == colmin);
            int colpos;
            if (__builtin_popcountll(m2) == 1) {
                colpos = __builtin_amdgcn_readlane(cp, __builtin_ctzll(m2));
            } else {
                unsigned long long kk =
                    ((unsigned long long)cv << 32) | (unsigned)cp;
#pragma unroll
                for (int m = 1; m < 64; m <<= 1) {
                    unsigned long long o = __shfl_xor(kk, m, 64);
                    kk = (o < kk) ? o : kk;
                }
                colpos = (int)(kk & 0xFFFFFFFFull);
            }
            if (l == own) { u0 = colmin; p0 = colpos; }
        }
    }

    // ---- Phase 4: final indices + gather into LDS ----
    if (l < GG) sidxs[l] = (resv > SORT_R2) ? pos0 : resp;   // radius filter
    __syncthreads();   // single-wave: ~free; orders sidxs/grouped

    if (l < 32) {
        int idx = sidxs[l];
        float4 p = pts4[(long)b * NN + idx];
        float4 rc = make_float4(__fsub_rn(p.x, q.x), __fsub_rn(p.y, q.y),
                                __fsub_rn(p.z, q.z), 0.f);
        *(float4*)&grouped[l * 68 + 64] = rc;
    }
    {
        int g = l >> 1, half = l & 1;
        int idx = sidxs[g];
        const float4* f4 = (const float4*)(feaT + ((long)b * NN + idx) * 64);
#pragma unroll
        for (int k4 = 0; k4 < 8; k4++) {
            *(float4*)&grouped[g * 68 + half * 32 + k4 * 4] = f4[half * 8 + k4];
        }
    }
    __syncthreads();

    // ---- Phase 5: 1x1 conv + relu + max over group (packed pk_fma) ----
    v2f mm = v2f{-1e30f, -1e30f};
#pragma unroll 2
    for (int g = 0; g < GG; g++) {
        v2f a = v2f{0.f, 0.f};
#pragma unroll
        for (int c4 = 0; c4 < 17; c4++) {
            float4 gv = *(float4*)&grouped[g * 68 + c4 * 4];
            a = __builtin_elementwise_fma(v2f{gv.x, gv.x}, wab[4 * c4 + 0], a);
            a = __builtin_elementwise_fma(v2f{gv.y, gv.y}, wab[4 * c4 + 1], a);
            a = __builtin_elementwise_fma(v2f{gv.z, gv.z}, wab[4 * c4 + 2], a);
            a = __builtin_elementwise_fma(v2f{gv.w, gv.w}, wab[4 * c4 + 3], a);
        }
        mm = __builtin_elementwise_max(mm, a);
    }
    // outputs: (B,3,S) then (B,128,S); relu(max) == max(relu)
    out[49152 + ((long)b * 128 + l) * SS + s]      = fmaxf(mm.x, 0.f);
    out[49152 + ((long)b * 128 + l + 64) * SS + s] = fmaxf(mm.y, 0.f);
}

// ---------------------------------------------------------------------------
extern "C" void kernel_launch(void* const* d_in, const int* in_sizes, int n_in,
                              void* d_out, int out_size, void* d_ws, size_t ws_size,
                              hipStream_t stream) {
    const float* coor = (const float*)d_in[0];   // (16,3,8192)
    const float* fea  = (const float*)d_in[1];   // (16,64,8192)
    const float* Wm   = (const float*)d_in[2];   // (128,67)
    float* out = (float*)d_out;

    char* ws = (char*)d_ws;
    float4* pts4 = (float4*)ws;                               //  2 MB
    float*  feaT = (float*)(ws + 2097152);                    // 32 MB
    float4* qpts = (float4*)(ws + 2097152 + 33554432);        // 256 KB

    k_pts<<<(BB * NN) / 256, 256, 0, stream>>>(coor, pts4);
    k_tr<<<dim3(NN / 64, BB), 256, 0, stream>>>(fea, feaT);
    k_fps<<<BB, 512, 0, stream>>>(pts4, qpts, out);
    k_knn_mlp<<<BB * SS, 64, 0, stream>>>(pts4, feaT, qpts, Wm, out);
}

// Round 13
// 1267.932 us; speedup vs baseline: 1.8270x; 1.0013x over previous
//
#include <hip/hip_runtime.h>
#include <hip/hip_bf16.h>

// Problem constants
#define BB 16
#define NN 8192
#define SS 1024
#define GG 32
// sortable(1.0f) = 0x3F800000 ^ 0x80000000
#define SORT_R2 0xBF800000u

typedef float v2f __attribute__((ext_vector_type(2)));

__device__ __forceinline__ unsigned sortable(float f) {
    unsigned u = __float_as_uint(f);
    return u ^ ((unsigned)(((int)u) >> 31) | 0x80000000u);
}

// f32 max-combine with a DPP-permuted copy (2 slots: v_mov_dpp + v_max_f32).
// row_shr:n = 0x110|n, row_bcast15 = 0x142, row_bcast31 = 0x143.
template <int CTRL, int RM>
__device__ __forceinline__ float dpp_maxf(float v) {
    int i = __float_as_int(v);
    int p = __builtin_amdgcn_update_dpp(i, i, CTRL, RM, 0xF, false);
    return fmaxf(v, __int_as_float(p));
}

// u32 min-combine with a DPP-permuted copy (2 slots).
template <int CTRL, int RM>
__device__ __forceinline__ unsigned dpp_minu(unsigned v) {
    int p = __builtin_amdgcn_update_dpp((int)v, (int)v, CTRL, RM, 0xF, false);
    return min(v, (unsigned)p);
}

__device__ __forceinline__ float fmax3(float a, float b, float c) {
    return fmaxf(fmaxf(a, b), c);   // fuses to v_max3_f32
}

// ---------------------------------------------------------------------------
// Kernel 1: pack pts4[b][n] = {x, y, z, (x*x+y*y)+z*z}  (rn ops, no contraction)
// ---------------------------------------------------------------------------
__global__ __launch_bounds__(256) void k_pts(const float* __restrict__ coor,
                                             float4* __restrict__ pts4) {
    int i = blockIdx.x * 256 + threadIdx.x;   // 0 .. B*N-1
    int b = i >> 13, n = i & (NN - 1);
    const float* cb = coor + (long)b * 3 * NN;
    float x = cb[n], y = cb[NN + n], z = cb[2 * NN + n];
    float pn = __fadd_rn(__fadd_rn(__fmul_rn(x, x), __fmul_rn(y, y)), __fmul_rn(z, z));
    pts4[i] = make_float4(x, y, z, pn);
}

// ---------------------------------------------------------------------------
// Kernel 2: transpose fea (B,64,N) -> feaT (B,N,64)
// ---------------------------------------------------------------------------
__global__ __launch_bounds__(256) void k_tr(const float* __restrict__ fea,
                                            float* __restrict__ feaT) {
    __shared__ float tile[64][65];
    int b = blockIdx.y, n0 = blockIdx.x * 64;
    int t = threadIdx.x;
    int nl = t & 63, cb = t >> 6;
#pragma unroll
    for (int i = 0; i < 16; i++) {
        int c = cb * 16 + i;
        tile[nl][c] = fea[((long)b * 64 + c) * NN + n0 + nl];
    }
    __syncthreads();
    int cl = t & 63, nb = t >> 6;
#pragma unroll
    for (int i = 0; i < 16; i++) {
        int n = nb * 16 + i;
        feaT[((long)b * NN + n0 + n) * 64 + cl] = tile[n][cl];
    }
}

// ---------------------------------------------------------------------------
// Kernel 3: farthest point sampling. One block (512 thr) per batch.
// R12 verbatim (measured optimum ~935 us; at its structural floor given
// the bit-exact fp formula constraint; six structural attacks regressed).
// ---------------------------------------------------------------------------
__global__ __launch_bounds__(512) void k_fps(const float4* __restrict__ pts4,
                                             float4* __restrict__ qpts,
                                             float* __restrict__ out) {
#pragma clang fp contract(off)
    __shared__ float xs[NN], ys[NN], zs[NN];
    __shared__ int scur[SS];
    __shared__ __align__(16) float redv[2][8];
    __shared__ int sidx[2];
    int b = blockIdx.x;
    int t = threadIdx.x;
    const float4* P = pts4 + (long)b * NN;

    // pair j, half h -> point p = t + (2j+h)*512
    v2f px[8], py[8], pz[8], dist[8];
#pragma unroll
    for (int j = 0; j < 8; j++) {
        int p0 = t + (2 * j) * 512;
        int p1 = t + (2 * j + 1) * 512;
        float4 a = P[p0];
        float4 c = P[p1];
        px[j] = v2f{a.x, c.x};
        py[j] = v2f{a.y, c.y};
        pz[j] = v2f{a.z, c.z};
        dist[j] = v2f{1e10f, 1e10f};
        xs[p0] = a.x; ys[p0] = a.y; zs[p0] = a.z;
        xs[p1] = c.x; ys[p1] = c.y; zs[p1] = c.z;
    }
    if (t == 0) { sidx[0] = 0x7FFFFFFF; sidx[1] = 0x7FFFFFFF; }
    __syncthreads();

    int cur = 0;
    for (int s = 0; s < SS; s++) {
        int par = s & 1;
        float cx = xs[cur], cy = ys[cur], cz = zs[cur];
        if (t == 0) scur[s] = cur;
        v2f cx2 = v2f{cx, cx}, cy2 = v2f{cy, cy}, cz2 = v2f{cz, cz};
#pragma unroll
        for (int j = 0; j < 8; j++) {
            v2f dx = px[j] - cx2;
            v2f dy = py[j] - cy2;
            v2f dz = pz[j] - cz2;
            v2f xx = dx * dx;
            v2f yy = dy * dy;
            v2f zz = dz * dz;
            v2f sm = xx + yy;
            v2f d = sm + zz;
            dist[j] = __builtin_elementwise_min(dist[j], d);
        }
        // value-only per-thread max: packed tree (7 pk-max) + final scalar
        v2f m01 = __builtin_elementwise_max(dist[0], dist[1]);
        v2f m23 = __builtin_elementwise_max(dist[2], dist[3]);
        v2f m45 = __builtin_elementwise_max(dist[4], dist[5]);
        v2f m67 = __builtin_elementwise_max(dist[6], dist[7]);
        v2f m03 = __builtin_elementwise_max(m01, m23);
        v2f m47 = __builtin_elementwise_max(m45, m67);
        v2f m07 = __builtin_elementwise_max(m03, m47);
        float bv = fmaxf(m07.x, m07.y);
        // 64-lane DPP f32 max; full-wave max lands in lane 63
        float wv = bv;
        wv = dpp_maxf<0x111, 0xF>(wv);   // row_shr:1
        wv = dpp_maxf<0x112, 0xF>(wv);   // row_shr:2
        wv = dpp_maxf<0x114, 0xF>(wv);   // row_shr:4
        wv = dpp_maxf<0x118, 0xF>(wv);   // row_shr:8
        wv = dpp_maxf<0x142, 0xA>(wv);   // row_bcast:15 (rows 1,3)
        wv = dpp_maxf<0x143, 0xC>(wv);   // row_bcast:31 (rows 2,3)
        if ((t & 63) == 63) redv[par][t >> 6] = wv;
        __syncthreads();                 // barrier 1
        float4 r0 = *(const float4*)redv[par];
        float4 r1 = *(const float4*)(redv[par] + 4);
        float gmax = fmaxf(fmax3(r0.x, r0.y, r0.z),
                           fmax3(r0.w, fmax3(r1.x, r1.y, r1.z), r1.w));
        // reset the OTHER sidx slot (used at s+1); barrier 2 separates it
        // from s+1's atomics.
        if (t == 0) sidx[1 - par] = 0x7FFFFFFF;
        if (bv == gmax) {
            // block-rare path (usually 1 thread): lowest matching ord
            int jj = 16;
#pragma unroll
            for (int j = 7; j >= 0; j--) {
                jj = (dist[j].y == gmax) ? (2 * j + 1) : jj;
                jj = (dist[j].x == gmax) ? (2 * j) : jj;
            }
            atomicMin(&sidx[par], t + jj * 512);
        }
        __syncthreads();                 // barrier 2
        cur = sidx[par];
    }
    __syncthreads();

    // epilogue: write new_coor (B,3,S) and query points from recorded indices
#pragma unroll
    for (int s = t; s < SS; s += 512) {
        int c = scur[s];
        float cx = xs[c], cy = ys[c], cz = zs[c];
        out[(long)b * 3 * SS + s]          = cx;
        out[(long)b * 3 * SS + SS + s]     = cy;
        out[(long)b * 3 * SS + 2 * SS + s] = cz;
        float qn = __fadd_rn(__fadd_rn(__fmul_rn(cx, cx), __fmul_rn(cy, cy)),
                             __fmul_rn(cz, cz));
        qpts[(long)b * SS + s] = make_float4(cx, cy, cz, qn);
    }
}

// ---------------------------------------------------------------------------
// Kernel 4 (FUSED knn+mlp). R21 = VERBATIM revert to the verified R16
// (benched 1269.6 us, absmax 0.0). Three epilogue/pairing rewrites
// (R17/R18/R20) all failed with the identical absmax 0.5703125 despite
// structurally different mechanisms — the equivalence model for that
// region is wrong in a way not diagnosable blind, so the line is
// abandoned and the known-good form re-banked. dk eliminated via top-2
// queues + recompute-refill; LDS = grouped(8704B)+sidxs(128B); ~18
// blocks/CU occupancy.
// ---------------------------------------------------------------------------
__global__ __launch_bounds__(64, 1) void k_knn_mlp(const float4* __restrict__ pts4,
                                                   const float* __restrict__ feaT,
                                                   const float4* __restrict__ qpts,
                                                   const float* __restrict__ W,
                                                   float* __restrict__ out) {
    __shared__ __align__(16) float grouped[GG * 68];   // 8704 B
    __shared__ int sidxs[GG];                          //  128 B

    int Q = blockIdx.x;                      // b*1024 + s
    int b = Q >> 10, s = Q & 1023;
    int l = threadIdx.x;
    float4 q = qpts[Q];
    const float4* P = pts4 + (long)b * NN;

    // ---- Phase 1: distance scan + per-lane top-2 (u0,p0)<(u1q,p1q) ----
    unsigned u0 = 0xFFFFFFFFu, u1q = 0xFFFFFFFFu;
    int p0 = 0, p1q = 0;
#pragma unroll 16
    for (int j = 0; j < 128; j++) {
        int p = j * 64 + l;
        float4 v = P[p];
        float dot = __fadd_rn(__fadd_rn(__fmul_rn(q.x, v.x), __fmul_rn(q.y, v.y)),
                              __fmul_rn(q.z, v.z));
        float d = __fadd_rn(__fsub_rn(q.w, __fmul_rn(2.0f, dot)), v.w);
        unsigned u = sortable(d);
        // sorted insert, ascending p scan; strict < keeps earliest pos on ties
        bool c0 = u < u0;
        bool c1 = u < u1q;
        u1q = c1 ? (c0 ? u0 : u) : u1q;
        p1q = c1 ? (c0 ? p0 : p) : p1q;
        u0 = c0 ? u : u0;
        p0 = c0 ? p : p0;
    }

    // ---- Phase 2: W rows into registers (latency overlaps pops) ----
    v2f wab[68];
    {
        const float* Wr = W + l * 67;
#pragma unroll
        for (int c = 0; c < 67; c++) {
            wab[c] = v2f{Wr[c], Wr[64 * 67 + c]};
        }
        wab[67] = v2f{0.f, 0.f};
    }

    // ---- Phase 3: 32 pops (queue common path; rare recompute-refill) ----
    // consLo/consHi: bit j set <=> point j*64+l consumed (this lane's column)
    unsigned long long consLo = 0ull, consHi = 0ull;
    unsigned resv = 0;
    int resp = 0, pos0 = 0;
    for (int k = 0; k < GG; k++) {
        unsigned mv = u0;
        mv = dpp_minu<0x111, 0xF>(mv);
        mv = dpp_minu<0x112, 0xF>(mv);
        mv = dpp_minu<0x114, 0xF>(mv);
        mv = dpp_minu<0x118, 0xF>(mv);
        mv = dpp_minu<0x142, 0xA>(mv);
        mv = dpp_minu<0x143, 0xC>(mv);
        unsigned wmin = (unsigned)__builtin_amdgcn_readlane((int)mv, 63);
        unsigned long long mask = __ballot(u0 == wmin);
        int wpos;
        if (__builtin_popcountll(mask) == 1) {
            int owner = __builtin_ctzll(mask);
            wpos = __builtin_amdgcn_readlane(p0, owner);
        } else {
            unsigned long long kk =
                ((unsigned long long)u0 << 32) | (unsigned)p0;
#pragma unroll
            for (int m = 1; m < 64; m <<= 1) {
                unsigned long long o = __shfl_xor(kk, m, 64);
                kk = (o < kk) ? o : kk;
            }
            wpos = (int)(kk & 0xFFFFFFFFull);
        }
        if (k == 0) pos0 = wpos;
        if (l == k) { resv = wmin; resp = wpos; }
        int own = wpos & 63;                   // p = j*64 + lane
        if (l == own) {
            int jj = wpos >> 6;                // consumed column slot
            if (jj < 64) consLo |= 1ull << jj;
            else         consHi |= 1ull << (jj - 64);
            u0 = u1q; p0 = p1q;                // promote 2nd -> head
            u1q = 0xFFFFFFFFu;
        }
        // owner's new head (0xFFFFFFFF unreachable for finite distances)
        unsigned oh = (unsigned)__builtin_amdgcn_readlane((int)u0, own);
        if (oh == 0xFFFFFFFFu) {
            // RARE: owner queue empty -> cooperative recompute of its column
            unsigned long long mLo = __shfl(consLo, own, 64);
            unsigned long long mHi = __shfl(consHi, own, 64);
            int rc1 = l * 64 + own;
            int rc2 = (l + 64) * 64 + own;
            float4 a1 = P[rc1];
            float4 a2 = P[rc2];
            float dot1 = __fadd_rn(__fadd_rn(__fmul_rn(q.x, a1.x), __fmul_rn(q.y, a1.y)),
                                   __fmul_rn(q.z, a1.z));
            float d1 = __fadd_rn(__fsub_rn(q.w, __fmul_rn(2.0f, dot1)), a1.w);
            unsigned uu1 = sortable(d1);
            float dot2 = __fadd_rn(__fadd_rn(__fmul_rn(q.x, a2.x), __fmul_rn(q.y, a2.y)),
                                   __fmul_rn(q.z, a2.z));
            float d2 = __fadd_rn(__fsub_rn(q.w, __fmul_rn(2.0f, dot2)), a2.w);
            unsigned uu2 = sortable(d2);
            if ((mLo >> l) & 1) uu1 = 0xFFFFFFFFu;
            if ((mHi >> l) & 1) uu2 = 0xFFFFFFFFu;
            bool c = uu2 < uu1;               // rc1 < rc2, tie keeps earliest
            unsigned cv = c ? uu2 : uu1;
            int cp = c ? rc2 : rc1;
            unsigned cm = cv;
            cm = dpp_minu<0x111, 0xF>(cm);
            cm = dpp_minu<0x112, 0xF>(cm);
            cm = dpp_minu<0x114, 0xF>(cm);
            cm = dpp_minu<0x118, 0xF>(cm);
            cm = dpp_minu<0x142, 0xA>(cm);
            cm = dpp_minu<0x143, 0xC>(cm);
            unsigned colmin = (unsigned)__builtin_amdgcn_readlane((int)cm, 63);
            unsigned long long m2 = __ballot(cv == colmin);
            int colpos;
            if (__builtin_popcountll(m2) == 1) {
                colpos = __builtin_amdgcn_readlane(cp, __builtin_ctzll(m2));
            } else {
                unsigned long long kk =
                    ((unsigned long long)cv << 32) | (unsigned)cp;
#pragma unroll
                for (int m = 1; m < 64; m <<= 1) {
                    unsigned long long o = __shfl_xor(kk, m, 64);
                    kk = (o < kk) ? o : kk;
                }
                colpos = (int)(kk & 0xFFFFFFFFull);
            }
            if (l == own) { u0 = colmin; p0 = colpos; }
        }
    }

    // ---- Phase 4: final indices + gather into LDS ----
    if (l < GG) sidxs[l] = (resv > SORT_R2) ? pos0 : resp;   // radius filter
    __syncthreads();   // single-wave: ~free; orders sidxs/grouped

    if (l < 32) {
        int idx = sidxs[l];
        float4 p = pts4[(long)b * NN + idx];
        float4 rc = make_float4(__fsub_rn(p.x, q.x), __fsub_rn(p.y, q.y),
                                __fsub_rn(p.z, q.z), 0.f);
        *(float4*)&grouped[l * 68 + 64] = rc;
    }
    {
        int g = l >> 1, half = l & 1;
        int idx = sidxs[g];
        const float4* f4 = (const float4*)(feaT + ((long)b * NN + idx) * 64);
#pragma unroll
        for (int k4 = 0; k4 < 8; k4++) {
            *(float4*)&grouped[g * 68 + half * 32 + k4 * 4] = f4[half * 8 + k4];
        }
    }
    __syncthreads();

    // ---- Phase 5: 1x1 conv + relu + max over group (packed pk_fma) ----
    v2f mm = v2f{-1e30f, -1e30f};
#pragma unroll 2
    for (int g = 0; g < GG; g++) {
        v2f a = v2f{0.f, 0.f};
#pragma unroll
        for (int c4 = 0; c4 < 17; c4++) {
            float4 gv = *(float4*)&grouped[g * 68 + c4 * 4];
            a = __builtin_elementwise_fma(v2f{gv.x, gv.x}, wab[4 * c4 + 0], a);
            a = __builtin_elementwise_fma(v2f{gv.y, gv.y}, wab[4 * c4 + 1], a);
            a = __builtin_elementwise_fma(v2f{gv.z, gv.z}, wab[4 * c4 + 2], a);
            a = __builtin_elementwise_fma(v2f{gv.w, gv.w}, wab[4 * c4 + 3], a);
        }
        mm = __builtin_elementwise_max(mm, a);
    }
    // outputs: (B,3,S) then (B,128,S); relu(max) == max(relu)
    out[49152 + ((long)b * 128 + l) * SS + s]      = fmaxf(mm.x, 0.f);
    out[49152 + ((long)b * 128 + l + 64) * SS + s] = fmaxf(mm.y, 0.f);
}

// ---------------------------------------------------------------------------
extern "C" void kernel_launch(void* const* d_in, const int* in_sizes, int n_in,
                              void* d_out, int out_size, void* d_ws, size_t ws_size,
                              hipStream_t stream) {
    const float* coor = (const float*)d_in[0];   // (16,3,8192)
    const float* fea  = (const float*)d_in[1];   // (16,64,8192)
    const float* Wm   = (const float*)d_in[2];   // (128,67)
    float* out = (float*)d_out;

    char* ws = (char*)d_ws;
    float4* pts4 = (float4*)ws;                               //  2 MB
    float*  feaT = (float*)(ws + 2097152);                    // 32 MB
    float4* qpts = (float4*)(ws + 2097152 + 33554432);        // 256 KB

    k_pts<<<(BB * NN) / 256, 256, 0, stream>>>(coor, pts4);
    k_tr<<<dim3(NN / 64, BB), 256, 0, stream>>>(fea, feaT);
    k_fps<<<BB, 512, 0, stream>>>(pts4, qpts, out);
    k_knn_mlp<<<BB * SS, 64, 0, stream>>>(pts4, feaT, qpts, Wm, out);
}